// Round 11
// baseline (165.948 us; speedup 1.0000x reference)
//
#include <hip/hip_runtime.h>
#include <hip/hip_bf16.h>
#include <float.h>
#include <stdint.h>

#define NEG_SLOPE 0.2f

typedef __attribute__((ext_vector_type(8))) short short8;
typedef __attribute__((ext_vector_type(4))) float f32x4;

#define BSTRIDE 3584  // padded per-bucket capacity (mean 2046 + node-pad <=896)

__device__ inline float b2f(unsigned short u) {
  return __uint_as_float((unsigned int)u << 16);
}
__device__ inline unsigned short f2b(float f) {
  unsigned int u = __float_as_uint(f);
  return (unsigned short)((u + 0x7FFF + ((u >> 16) & 1)) >> 16);
}
__device__ inline float leaky(float e) { return e >= 0.f ? e : NEG_SLOPE * e; }
__device__ inline float blo(unsigned int w) {
  return __uint_as_float(w << 16);
}
__device__ inline float bhi(unsigned int w) {
  return __uint_as_float(w & 0xFFFF0000u);
}

__device__ inline int load_idx(const void* ei, long long pos, int is64) {
  if (is64) return (int)((const long long*)ei)[pos];
  return ((const int*)ei)[pos];
}

// ---------------------------------------------------------------------------
// One-shot prep:
//   blocks [0,128)   : pack W1 -> Wp1 fragment layout
//   blocks [128,256) : pack W2 -> Wp2
//   blocks [256,259) : wa[768] = {W1@a1s, W1@a1d, W2@a2s, W2@a2d}
//   block 259        : zero bcur[512]; detect int64 edge_index (ballot)
// ---------------------------------------------------------------------------
__global__ __launch_bounds__(256) void prep_all(
    const float* __restrict__ W1, const float* __restrict__ W2,
    const float* __restrict__ a1s, const float* __restrict__ a1d,
    const float* __restrict__ a2s, const float* __restrict__ a2d,
    unsigned short* __restrict__ Wp1, unsigned short* __restrict__ Wp2,
    float* __restrict__ wa, int* __restrict__ bcur, const void* __restrict__ ei,
    int* __restrict__ flag64) {
  int b = blockIdx.x;
  int t = threadIdx.x;
  if (b < 128) {
    int i = b * 256 + t;
    int k = i >> 8, n = i & 255;
    Wp1[(((k >> 3) * 256 + n) << 3) + (k & 7)] = f2b(W1[i]);
  } else if (b < 256) {
    int i = (b - 128) * 256 + t;
    int k = i >> 7, n = i & 127;
    Wp2[(((k >> 3) * 128 + n) << 3) + (k & 7)] = f2b(W2[i]);
  } else if (b < 259) {
    int o = (b - 256) * 256 + t;
    float s = 0.f;
    if (o < 128) {
      for (int n = 0; n < 256; ++n) s += W1[o * 256 + n] * a1s[n];
    } else if (o < 256) {
      int k = o - 128;
      for (int n = 0; n < 256; ++n) s += W1[k * 256 + n] * a1d[n];
    } else if (o < 512) {
      int k = o - 256;
      for (int n = 0; n < 128; ++n) s += W2[k * 128 + n] * a2s[n];
    } else {
      int k = o - 512;
      for (int n = 0; n < 128; ++n) s += W2[k * 128 + n] * a2d[n];
    }
    wa[o] = s;
  } else {
    bcur[t] = 0;
    bcur[t + 256] = 0;
    if (t < 64) {
      const int* p = (const int*)ei;
      unsigned long long bl = __ballot(p[2 * t + 1] != 0);
      if (t == 0) *flag64 = (bl == 0ull) ? 1 : 0;
    }
  }
}

// ===========================================================================
// Fused dispatch: blocks [0,nblk) bin edges into bucket regions (bucket =
// dst>>7, XCD-exclusive downstream writes); blocks [nblk, nblk+nb4) compute
// layer-1 scores + bf16 cast of x. Independent work, one launch.
// ===========================================================================
__global__ __launch_bounds__(256) void bin_and_alpha(
    const void* __restrict__ ei, const int* __restrict__ flag64, int E,
    int* __restrict__ bcursor, unsigned int* __restrict__ binned, int nblk,
    const float* __restrict__ x, const float* __restrict__ wa,
    unsigned short* __restrict__ xb, float* __restrict__ as_out,
    float* __restrict__ ad_out, int Nn) {
  __shared__ int hist[512];
  __shared__ int scn[512];
  __shared__ int gb[512];
  __shared__ unsigned int stage[2048];
  int t = threadIdx.x;
  if (blockIdx.x >= nblk) {
    // ---- alpha1 + cast part ----
    int node = (blockIdx.x - nblk) * 4 + (t >> 6);
    int lane = t & 63;
    if (node >= Nn) return;
    float2 v = *(const float2*)(x + (long long)node * 128 + lane * 2);
    float s1 = v.x * wa[lane * 2] + v.y * wa[lane * 2 + 1];
    float s2 = v.x * wa[128 + lane * 2] + v.y * wa[128 + lane * 2 + 1];
    unsigned int packed =
        (unsigned int)f2b(v.x) | ((unsigned int)f2b(v.y) << 16);
    *(unsigned int*)(xb + (long long)node * 128 + lane * 2) = packed;
#pragma unroll
    for (int off = 32; off > 0; off >>= 1) {
      s1 += __shfl_down(s1, off);
      s2 += __shfl_down(s2, off);
    }
    if (lane == 0) {
      as_out[node] = s1;
      ad_out[node] = s2;
    }
    return;
  }
  // ---- bin_edges part ----
  hist[t] = 0; hist[t + 256] = 0;
  __syncthreads();
  const int is64 = *flag64;
  const long long base = (long long)blockIdx.x * 2048;
  const int cblk = (int)min((long long)2048, (long long)E - base);
  int sv[8];
  short bk[8], rk[8];
#pragma unroll
  for (int i = 0; i < 8; ++i) {
    int k = t + i * 256;
    if (k < cblk) {
      long long j = base + k;
      int s = load_idx(ei, j, is64);
      int d = load_idx(ei, (long long)E + j, is64);
      int b = d >> 7;
      bk[i] = (short)b;
      sv[i] = (s << 7) | (d & 127);
      rk[i] = (short)atomicAdd(&hist[b], 1);
    } else {
      bk[i] = -1;
    }
  }
  __syncthreads();
  scn[t] = hist[t]; scn[t + 256] = hist[t + 256];
  __syncthreads();
  for (int off = 1; off < 512; off <<= 1) {
    int v0 = (t >= off) ? scn[t - off] : 0;
    int v1 = scn[t + 256 - off];
    __syncthreads();
    scn[t] += v0;
    scn[t + 256] += v1;
    __syncthreads();
  }
  int c0 = hist[t], c1 = hist[t + 256];
  int l0 = scn[t] - c0, l1 = scn[t + 256] - c1;
  if (c0) gb[t] = atomicAdd(&bcursor[t], c0);
  if (c1) gb[t + 256] = atomicAdd(&bcursor[t + 256], c1);
  scn[t] = l0; scn[t + 256] = l1;
  __syncthreads();
#pragma unroll
  for (int i = 0; i < 8; ++i) {
    if (bk[i] >= 0)
      stage[scn[bk[i]] + rk[i]] = ((unsigned)(int)bk[i] << 23) | (unsigned)sv[i];
  }
  __syncthreads();
#pragma unroll
  for (int i = 0; i < 8; ++i) {
    int k = t + i * 256;
    if (k < cblk) {
      unsigned w = stage[k];
      int b = w >> 23;
      binned[(long long)b * BSTRIDE + gb[b] + (k - scn[b])] = w;
    }
  }
}

// ---------------------------------------------------------------------------
// place_csr: one block per bucket. Per-node degree + LDS scan with each
// node's csr segment start aligned to 8 entries (16B); pad slots zeroed so
// the aggregate can read whole uint4 index groups safely.
// ---------------------------------------------------------------------------
__global__ __launch_bounds__(256) void place_csr(
    const unsigned int* __restrict__ binned, const int* __restrict__ bcursor,
    int2* __restrict__ rowbe, unsigned short* __restrict__ csr, int Nn) {
  __shared__ int cnt[128], deg0[128], cur[128], alc[128];
  int t = threadIdx.x;
  int b = blockIdx.x;
  if (t < 128) cnt[t] = 0;
  __syncthreads();
  const int rbeg = b * BSTRIDE;
  const int rend = rbeg + bcursor[b];
  for (int k = rbeg + t; k < rend; k += 256)
    atomicAdd(&cnt[binned[k] & 127], 1);
  __syncthreads();
  if (t < 128) {
    deg0[t] = cnt[t];
    alc[t] = (cnt[t] + 7) & ~7;  // 8-aligned allocation
    cnt[t] = alc[t];
  }
  __syncthreads();
  for (int off = 1; off < 128; off <<= 1) {
    int v = (t >= off && t < 128) ? cnt[t - off] : 0;
    __syncthreads();
    if (t < 128) cnt[t] += v;
    __syncthreads();
  }
  const int node0 = b << 7;
  if (t < 128) {
    int start = rbeg + cnt[t] - alc[t];
    int node = node0 + t;
    if (node < Nn) rowbe[node] = make_int2(start, start + deg0[t]);
    cur[t] = start;
  }
  __syncthreads();
  for (int k = rbeg + t; k < rend; k += 256) {
    unsigned w = binned[k];
    int pos = atomicAdd(&cur[w & 127], 1);
    csr[pos] = (unsigned short)((w >> 7) & 0xFFFF);
  }
  __syncthreads();
  if (t < 128 && (node0 + t) < Nn) {
    int s0 = cur[t];          // start + deg
    int s1 = rbeg + cnt[t];   // start + alloc
    for (int k = s0; k < s1; ++k) csr[k] = 0;  // zero pads (masked in agg)
  }
}

// ---------------------------------------------------------------------------
// MFMA bf16 GEMM, fragments direct from global, NT n-tiles per wave
// (BN = 16*NT). Optional bias+ReLU epilogue. SCORES (deterministic,
// atomic-free): per-lane partial dots of A-rows with was/wad over K,
// shfl-reduce across the 4 k-groups, blockIdx.y==0 stores.
// ---------------------------------------------------------------------------
template <int Nn, int Kk, int NT, bool BIAS_RELU, bool SCORES>
__global__ __launch_bounds__(256) void gemm_mfma(
    const unsigned short* __restrict__ A, const unsigned short* __restrict__ Bp,
    unsigned short* __restrict__ C, int M, const float* __restrict__ bias,
    const float* __restrict__ was, const float* __restrict__ wad,
    float* __restrict__ s_as, float* __restrict__ s_ad) {
  const int l = threadIdx.x & 63;
  const int wm = threadIdx.x >> 6;
  const int bm = blockIdx.x * 64;
  const int bn = blockIdx.y * (16 * NT);
  const int arow = bm + wm * 16 + (l & 15);
  const int kg = l >> 4;

  f32x4 acc[NT];
#pragma unroll
  for (int nt = 0; nt < NT; ++nt) acc[nt] = (f32x4){0.f, 0.f, 0.f, 0.f};

  const bool arow_ok = (arow < M);
  const bool do_scores = SCORES && (blockIdx.y == 0);
  float ps = 0.f, pd = 0.f;
#pragma unroll
  for (int kk = 0; kk < Kk; kk += 32) {
    short8 afrag;
    if (arow_ok)
      afrag = *(const short8*)(A + (long long)arow * Kk + kk + kg * 8);
    else
      afrag = (short8){0, 0, 0, 0, 0, 0, 0, 0};
    if (SCORES) {
      if (do_scores) {
        const int kb0 = kk + kg * 8;
#pragma unroll
        for (int i = 0; i < 8; ++i) {
          float v = b2f((unsigned short)afrag[i]);
          ps += v * was[kb0 + i];
          pd += v * wad[kb0 + i];
        }
      }
    }
    const int kb = (kk >> 3) + kg;
#pragma unroll
    for (int nt = 0; nt < NT; ++nt) {
      short8 bfrag = *(const short8*)(Bp + (((long long)kb * Nn + bn + nt * 16 +
                                             (l & 15))
                                            << 3));
      acc[nt] = __builtin_amdgcn_mfma_f32_16x16x32_bf16(afrag, bfrag, acc[nt],
                                                        0, 0, 0);
    }
  }
  if (SCORES) {
    if (do_scores) {
      ps += __shfl_xor(ps, 16); ps += __shfl_xor(ps, 32);
      pd += __shfl_xor(pd, 16); pd += __shfl_xor(pd, 32);
      if (l < 16 && arow_ok) {
        s_as[arow] = ps;
        s_ad[arow] = pd;
      }
    }
  }
#pragma unroll
  for (int nt = 0; nt < NT; ++nt) {
    const int col = bn + nt * 16 + (l & 15);
    float bv = BIAS_RELU ? bias[col] : 0.f;
#pragma unroll
    for (int r = 0; r < 4; ++r) {
      const int row = bm + wm * 16 + (l >> 4) * 4 + r;
      if (row < M) {
        float v = acc[nt][r];
        if (BIAS_RELU) v = fmaxf(v + bv, 0.f);
        C[(long long)row * Nn + col] = f2b(v);
      }
    }
  }
}

// ---------------------------------------------------------------------------
// Single-pass flash-style softmax + gather-aggregate. One 16-lane group per
// node. Index stream read as uint4 (8 edges/load, segments 8-aligned with
// zeroed pads); NEXT index vector prefetched before processing the current
// batch so the csr-load hop is off the steady-state critical chain. 8
// independent 256B row loads in flight. Deferred-max threshold 8.
// ---------------------------------------------------------------------------
template <bool BIAS_RELU, bool OUT_BF16>
__global__ __launch_bounds__(256) void gat_aggregate(
    const int2* __restrict__ rowbe, const unsigned short* __restrict__ csr,
    const float* __restrict__ as, const float* __restrict__ ad,
    const unsigned short* __restrict__ h, const float* __restrict__ bias,
    void* __restrict__ outp, int Nn) {
  constexpr int F = 128;
  const int node = blockIdx.x * 16 + (threadIdx.x >> 4);
  const int hl = threadIdx.x & 15;
  if (node >= Nn) return;
  const int2 be = rowbe[node];
  const int beg = be.x, end = be.y;
  const float adn = ad[node];
  const int f0 = hl * 8;

  // self-loop seed
  float m = leaky(as[node] + adn);
  float sg = 1.f;
  float acc[8];
  {
    uint4 w = *(const uint4*)(h + (long long)node * F + f0);
    acc[0] = blo(w.x); acc[1] = bhi(w.x);
    acc[2] = blo(w.y); acc[3] = bhi(w.y);
    acc[4] = blo(w.z); acc[5] = bhi(w.z);
    acc[6] = blo(w.w); acc[7] = bhi(w.w);
  }

  int t = beg;
  uint4 c;
  if (t < end) c = *(const uint4*)(csr + t);
  while (t < end) {
    // prefetch next index vector (off the critical chain)
    uint4 cn;
    if (t + 8 < end) cn = *(const uint4*)(csr + t + 8);
    int s[8];
    s[0] = c.x & 0xFFFF; s[1] = c.x >> 16;
    s[2] = c.y & 0xFFFF; s[3] = c.y >> 16;
    s[4] = c.z & 0xFFFF; s[5] = c.z >> 16;
    s[6] = c.w & 0xFFFF; s[7] = c.w >> 16;
    uint4 w[8];
#pragma unroll
    for (int i = 0; i < 8; ++i)
      w[i] = *(const uint4*)(h + (long long)s[i] * F + f0);
    float e[8];
#pragma unroll
    for (int i = 0; i < 8; ++i)
      e[i] = (t + i < end) ? leaky(as[s[i]] + adn) : -3.4e38f;
    float em = e[0];
#pragma unroll
    for (int i = 1; i < 8; ++i) em = fmaxf(em, e[i]);
    if (em > m + 8.f) {  // deferred-max rescale (rare)
      float sc = __expf(m - em);
      sg *= sc;
#pragma unroll
      for (int j = 0; j < 8; ++j) acc[j] *= sc;
      m = em;
    }
    float p[8];
#pragma unroll
    for (int i = 0; i < 8; ++i) p[i] = __expf(e[i] - m);
#pragma unroll
    for (int i = 0; i < 8; ++i) sg += p[i];
#pragma unroll
    for (int i = 0; i < 8; ++i) {
      acc[0] += p[i] * blo(w[i].x); acc[1] += p[i] * bhi(w[i].x);
      acc[2] += p[i] * blo(w[i].y); acc[3] += p[i] * bhi(w[i].y);
      acc[4] += p[i] * blo(w[i].z); acc[5] += p[i] * bhi(w[i].z);
      acc[6] += p[i] * blo(w[i].w); acc[7] += p[i] * bhi(w[i].w);
    }
    c = cn;
    t += 8;
  }

  const float inv = 1.f / (sg + 1e-16f);
#pragma unroll
  for (int j = 0; j < 8; ++j) {
    acc[j] *= inv;
    if (BIAS_RELU) acc[j] = fmaxf(acc[j] + bias[f0 + j], 0.f);
  }
  if (OUT_BF16) {
    short8 o;
#pragma unroll
    for (int j = 0; j < 8; ++j) o[j] = (short)f2b(acc[j]);
    *(short8*)((unsigned short*)outp + (long long)node * F + f0) = o;
  } else {
    float4 o0 = {acc[0], acc[1], acc[2], acc[3]};
    float4 o1 = {acc[4], acc[5], acc[6], acc[7]};
    float* orow = (float*)outp + (long long)node * F + f0;
    *(float4*)(orow) = o0;
    *(float4*)(orow + 4) = o1;
  }
}

extern "C" void kernel_launch(void* const* d_in, const int* in_sizes, int n_in,
                              void* d_out, int out_size, void* d_ws,
                              size_t ws_size, hipStream_t stream) {
  const float* x      = (const float*)d_in[0];
  const void*  ei     = d_in[1];
  const float* W1     = (const float*)d_in[2];
  const float* a1_src = (const float*)d_in[3];
  const float* a1_dst = (const float*)d_in[4];
  const float* b1     = (const float*)d_in[5];
  const float* W2     = (const float*)d_in[6];
  const float* a2_src = (const float*)d_in[7];
  const float* a2_dst = (const float*)d_in[8];
  const float* b2     = (const float*)d_in[9];
  float* out = (float*)d_out;

  const int N = 50000, E = 800000, IN = 128, HID = 256, OUT = 128;
  const int NBLK_E = (E + 2047) / 2048;
  const int NB = (N + 127) >> 7;
  const int nb4 = (N + 3) / 4;
  const int nb16 = (N + 15) / 16;

  char* ws = (char*)d_ws;
  size_t off = 0;
  auto carve = [&](size_t bytes) -> void* {
    void* p = ws + off;
    off = (off + bytes + 255) & ~(size_t)255;
    return p;
  };
  unsigned short* xb     = (unsigned short*)carve((size_t)N * IN * 2);
  unsigned short* aggx   = (unsigned short*)carve((size_t)N * IN * 2);
  unsigned short* out1   = (unsigned short*)carve((size_t)N * HID * 2);
  unsigned short* h2     = (unsigned short*)carve((size_t)N * OUT * 2);
  unsigned short* Wp1    = (unsigned short*)carve((size_t)IN * HID * 2);
  unsigned short* Wp2    = (unsigned short*)carve((size_t)HID * OUT * 2);
  float*          wa     = (float*)carve(768 * 4);
  unsigned int*   binned = (unsigned int*)carve((size_t)NB * BSTRIDE * 4);
  unsigned short* csr    = (unsigned short*)carve((size_t)NB * BSTRIDE * 2);
  int*            bcur   = (int*)carve(512 * 4);
  int2*           rowbe  = (int2*)carve((size_t)N * 8);
  float*          as_    = (float*)carve((size_t)N * 4);
  float*          ad_    = (float*)carve((size_t)N * 4);
  float*          as2_   = (float*)carve((size_t)N * 4);
  float*          ad2_   = (float*)carve((size_t)N * 4);
  int*            flag64 = (int*)carve(256);
  (void)ws_size; (void)in_sizes; (void)n_in; (void)out_size;

  // ---- prep (weights pack + matvecs + bcur zero + idx64 detect) ----
  prep_all<<<260, 256, 0, stream>>>(W1, W2, a1_src, a1_dst, a2_src, a2_dst,
                                    Wp1, Wp2, wa, bcur, ei, flag64);

  // ---- fused: edge binning + layer-1 scores/cast ----
  bin_and_alpha<<<NBLK_E + nb4, 256, 0, stream>>>(
      ei, flag64, E, bcur, binned, NBLK_E, x, wa, xb, as_, ad_, N);

  // ---- CSR finalize (8-aligned, zero-padded segments) ----
  place_csr<<<NB, 256, 0, stream>>>(binned, bcur, rowbe, csr, N);

  // ---- layer 1: aggregate x, GEMM(+bias+ReLU), BN=128 ----
  gat_aggregate<false, true><<<nb16, 256, 0, stream>>>(rowbe, csr, as_, ad_,
                                                       xb, nullptr, aggx, N);
  {
    dim3 g((N + 63) / 64, HID / 128);
    gemm_mfma<HID, IN, 8, true, false><<<g, 256, 0, stream>>>(
        aggx, Wp1, out1, N, b1, nullptr, nullptr, nullptr, nullptr);
  }

  // ---- layer 2: GEMM BN=128 (+deterministic fused scores), aggregate ----
  {
    dim3 g((N + 63) / 64, OUT / 128);
    gemm_mfma<OUT, HID, 8, false, true><<<g, 256, 0, stream>>>(
        out1, Wp2, h2, N, nullptr, wa + 256, wa + 512, as2_, ad2_);
  }
  gat_aggregate<true, false><<<nb16, 256, 0, stream>>>(rowbe, csr, as2_,
                                                       ad2_, h2, b2, out, N);
}

// Round 12
// 146.091 us; speedup vs baseline: 1.1359x; 1.1359x over previous
//
#include <hip/hip_runtime.h>
#include <hip/hip_bf16.h>
#include <float.h>
#include <stdint.h>

#define NEG_SLOPE 0.2f

typedef __attribute__((ext_vector_type(8))) short short8;
typedef __attribute__((ext_vector_type(4))) float f32x4;

#define BSTRIDE 3584  // padded per-bucket capacity (mean 2046 + node-pad <=896)

__device__ inline float b2f(unsigned short u) {
  return __uint_as_float((unsigned int)u << 16);
}
__device__ inline unsigned short f2b(float f) {
  unsigned int u = __float_as_uint(f);
  return (unsigned short)((u + 0x7FFF + ((u >> 16) & 1)) >> 16);
}
__device__ inline float leaky(float e) { return e >= 0.f ? e : NEG_SLOPE * e; }
__device__ inline float blo(unsigned int w) {
  return __uint_as_float(w << 16);
}
__device__ inline float bhi(unsigned int w) {
  return __uint_as_float(w & 0xFFFF0000u);
}

__device__ inline int load_idx(const void* ei, long long pos, int is64) {
  if (is64) return (int)((const long long*)ei)[pos];
  return ((const int*)ei)[pos];
}

// ---------------------------------------------------------------------------
// One-shot prep:
//   blocks [0,128)   : pack W1 -> Wp1 fragment layout
//   blocks [128,256) : pack W2 -> Wp2
//   blocks [256,259) : wa[768] = {W1@a1s, W1@a1d, W2@a2s, W2@a2d}
//   block 259        : zero bcur[512]; detect int64 edge_index (ballot)
// ---------------------------------------------------------------------------
__global__ __launch_bounds__(256) void prep_all(
    const float* __restrict__ W1, const float* __restrict__ W2,
    const float* __restrict__ a1s, const float* __restrict__ a1d,
    const float* __restrict__ a2s, const float* __restrict__ a2d,
    unsigned short* __restrict__ Wp1, unsigned short* __restrict__ Wp2,
    float* __restrict__ wa, int* __restrict__ bcur, const void* __restrict__ ei,
    int* __restrict__ flag64) {
  int b = blockIdx.x;
  int t = threadIdx.x;
  if (b < 128) {
    int i = b * 256 + t;
    int k = i >> 8, n = i & 255;
    Wp1[(((k >> 3) * 256 + n) << 3) + (k & 7)] = f2b(W1[i]);
  } else if (b < 256) {
    int i = (b - 128) * 256 + t;
    int k = i >> 7, n = i & 127;
    Wp2[(((k >> 3) * 128 + n) << 3) + (k & 7)] = f2b(W2[i]);
  } else if (b < 259) {
    int o = (b - 256) * 256 + t;
    float s = 0.f;
    if (o < 128) {
      for (int n = 0; n < 256; ++n) s += W1[o * 256 + n] * a1s[n];
    } else if (o < 256) {
      int k = o - 128;
      for (int n = 0; n < 256; ++n) s += W1[k * 256 + n] * a1d[n];
    } else if (o < 512) {
      int k = o - 256;
      for (int n = 0; n < 128; ++n) s += W2[k * 128 + n] * a2s[n];
    } else {
      int k = o - 512;
      for (int n = 0; n < 128; ++n) s += W2[k * 128 + n] * a2d[n];
    }
    wa[o] = s;
  } else {
    bcur[t] = 0;
    bcur[t + 256] = 0;
    if (t < 64) {
      const int* p = (const int*)ei;
      unsigned long long bl = __ballot(p[2 * t + 1] != 0);
      if (t == 0) *flag64 = (bl == 0ull) ? 1 : 0;
    }
  }
}

// ===========================================================================
// Fused dispatch: blocks [0,nblk) bin edges into bucket regions (bucket =
// dst>>7, XCD-exclusive downstream writes); blocks [nblk, nblk+nb4) compute
// layer-1 scores + bf16 cast of x. Independent work, one launch.
// ===========================================================================
__global__ __launch_bounds__(256) void bin_and_alpha(
    const void* __restrict__ ei, const int* __restrict__ flag64, int E,
    int* __restrict__ bcursor, unsigned int* __restrict__ binned, int nblk,
    const float* __restrict__ x, const float* __restrict__ wa,
    unsigned short* __restrict__ xb, float* __restrict__ as_out,
    float* __restrict__ ad_out, int Nn) {
  __shared__ int hist[512];
  __shared__ int scn[512];
  __shared__ int gb[512];
  __shared__ unsigned int stage[2048];
  int t = threadIdx.x;
  if (blockIdx.x >= nblk) {
    // ---- alpha1 + cast part ----
    int node = (blockIdx.x - nblk) * 4 + (t >> 6);
    int lane = t & 63;
    if (node >= Nn) return;
    float2 v = *(const float2*)(x + (long long)node * 128 + lane * 2);
    float s1 = v.x * wa[lane * 2] + v.y * wa[lane * 2 + 1];
    float s2 = v.x * wa[128 + lane * 2] + v.y * wa[128 + lane * 2 + 1];
    unsigned int packed =
        (unsigned int)f2b(v.x) | ((unsigned int)f2b(v.y) << 16);
    *(unsigned int*)(xb + (long long)node * 128 + lane * 2) = packed;
#pragma unroll
    for (int off = 32; off > 0; off >>= 1) {
      s1 += __shfl_down(s1, off);
      s2 += __shfl_down(s2, off);
    }
    if (lane == 0) {
      as_out[node] = s1;
      ad_out[node] = s2;
    }
    return;
  }
  // ---- bin_edges part ----
  hist[t] = 0; hist[t + 256] = 0;
  __syncthreads();
  const int is64 = *flag64;
  const long long base = (long long)blockIdx.x * 2048;
  const int cblk = (int)min((long long)2048, (long long)E - base);
  int sv[8];
  short bk[8], rk[8];
#pragma unroll
  for (int i = 0; i < 8; ++i) {
    int k = t + i * 256;
    if (k < cblk) {
      long long j = base + k;
      int s = load_idx(ei, j, is64);
      int d = load_idx(ei, (long long)E + j, is64);
      int b = d >> 7;
      bk[i] = (short)b;
      sv[i] = (s << 7) | (d & 127);
      rk[i] = (short)atomicAdd(&hist[b], 1);
    } else {
      bk[i] = -1;
    }
  }
  __syncthreads();
  scn[t] = hist[t]; scn[t + 256] = hist[t + 256];
  __syncthreads();
  for (int off = 1; off < 512; off <<= 1) {
    int v0 = (t >= off) ? scn[t - off] : 0;
    int v1 = scn[t + 256 - off];
    __syncthreads();
    scn[t] += v0;
    scn[t + 256] += v1;
    __syncthreads();
  }
  int c0 = hist[t], c1 = hist[t + 256];
  int l0 = scn[t] - c0, l1 = scn[t + 256] - c1;
  if (c0) gb[t] = atomicAdd(&bcursor[t], c0);
  if (c1) gb[t + 256] = atomicAdd(&bcursor[t + 256], c1);
  scn[t] = l0; scn[t + 256] = l1;
  __syncthreads();
#pragma unroll
  for (int i = 0; i < 8; ++i) {
    if (bk[i] >= 0)
      stage[scn[bk[i]] + rk[i]] = ((unsigned)(int)bk[i] << 23) | (unsigned)sv[i];
  }
  __syncthreads();
#pragma unroll
  for (int i = 0; i < 8; ++i) {
    int k = t + i * 256;
    if (k < cblk) {
      unsigned w = stage[k];
      int b = w >> 23;
      binned[(long long)b * BSTRIDE + gb[b] + (k - scn[b])] = w;
    }
  }
}

// ---------------------------------------------------------------------------
// place_csr: one block per bucket. Per-node degree + LDS scan with each
// node's csr segment start aligned to 8 entries (16B); pad slots zeroed so
// the aggregate can read whole uint4 index groups safely.
// ---------------------------------------------------------------------------
__global__ __launch_bounds__(256) void place_csr(
    const unsigned int* __restrict__ binned, const int* __restrict__ bcursor,
    int2* __restrict__ rowbe, unsigned short* __restrict__ csr, int Nn) {
  __shared__ int cnt[128], deg0[128], cur[128], alc[128];
  int t = threadIdx.x;
  int b = blockIdx.x;
  if (t < 128) cnt[t] = 0;
  __syncthreads();
  const int rbeg = b * BSTRIDE;
  const int rend = rbeg + bcursor[b];
  for (int k = rbeg + t; k < rend; k += 256)
    atomicAdd(&cnt[binned[k] & 127], 1);
  __syncthreads();
  if (t < 128) {
    deg0[t] = cnt[t];
    alc[t] = (cnt[t] + 7) & ~7;  // 8-aligned allocation
    cnt[t] = alc[t];
  }
  __syncthreads();
  for (int off = 1; off < 128; off <<= 1) {
    int v = (t >= off && t < 128) ? cnt[t - off] : 0;
    __syncthreads();
    if (t < 128) cnt[t] += v;
    __syncthreads();
  }
  const int node0 = b << 7;
  if (t < 128) {
    int start = rbeg + cnt[t] - alc[t];
    int node = node0 + t;
    if (node < Nn) rowbe[node] = make_int2(start, start + deg0[t]);
    cur[t] = start;
  }
  __syncthreads();
  for (int k = rbeg + t; k < rend; k += 256) {
    unsigned w = binned[k];
    int pos = atomicAdd(&cur[w & 127], 1);
    csr[pos] = (unsigned short)((w >> 7) & 0xFFFF);
  }
  __syncthreads();
  if (t < 128 && (node0 + t) < Nn) {
    int s0 = cur[t];          // start + deg
    int s1 = rbeg + cnt[t];   // start + alloc
    for (int k = s0; k < s1; ++k) csr[k] = 0;  // zero pads (masked in agg)
  }
}

// ---------------------------------------------------------------------------
// MFMA bf16 GEMM, fragments direct from global, NT n-tiles per wave
// (BN = 16*NT). Optional bias+ReLU epilogue. SCORES (deterministic,
// atomic-free): per-lane partial dots of A-rows with was/wad over K,
// shfl-reduce across the 4 k-groups, blockIdx.y==0 stores.
// ---------------------------------------------------------------------------
template <int Nn, int Kk, int NT, bool BIAS_RELU, bool SCORES>
__global__ __launch_bounds__(256) void gemm_mfma(
    const unsigned short* __restrict__ A, const unsigned short* __restrict__ Bp,
    unsigned short* __restrict__ C, int M, const float* __restrict__ bias,
    const float* __restrict__ was, const float* __restrict__ wad,
    float* __restrict__ s_as, float* __restrict__ s_ad) {
  const int l = threadIdx.x & 63;
  const int wm = threadIdx.x >> 6;
  const int bm = blockIdx.x * 64;
  const int bn = blockIdx.y * (16 * NT);
  const int arow = bm + wm * 16 + (l & 15);
  const int kg = l >> 4;

  f32x4 acc[NT];
#pragma unroll
  for (int nt = 0; nt < NT; ++nt) acc[nt] = (f32x4){0.f, 0.f, 0.f, 0.f};

  const bool arow_ok = (arow < M);
  const bool do_scores = SCORES && (blockIdx.y == 0);
  float ps = 0.f, pd = 0.f;
#pragma unroll
  for (int kk = 0; kk < Kk; kk += 32) {
    short8 afrag;
    if (arow_ok)
      afrag = *(const short8*)(A + (long long)arow * Kk + kk + kg * 8);
    else
      afrag = (short8){0, 0, 0, 0, 0, 0, 0, 0};
    if (SCORES) {
      if (do_scores) {
        const int kb0 = kk + kg * 8;
#pragma unroll
        for (int i = 0; i < 8; ++i) {
          float v = b2f((unsigned short)afrag[i]);
          ps += v * was[kb0 + i];
          pd += v * wad[kb0 + i];
        }
      }
    }
    const int kb = (kk >> 3) + kg;
#pragma unroll
    for (int nt = 0; nt < NT; ++nt) {
      short8 bfrag = *(const short8*)(Bp + (((long long)kb * Nn + bn + nt * 16 +
                                             (l & 15))
                                            << 3));
      acc[nt] = __builtin_amdgcn_mfma_f32_16x16x32_bf16(afrag, bfrag, acc[nt],
                                                        0, 0, 0);
    }
  }
  if (SCORES) {
    if (do_scores) {
      ps += __shfl_xor(ps, 16); ps += __shfl_xor(ps, 32);
      pd += __shfl_xor(pd, 16); pd += __shfl_xor(pd, 32);
      if (l < 16 && arow_ok) {
        s_as[arow] = ps;
        s_ad[arow] = pd;
      }
    }
  }
#pragma unroll
  for (int nt = 0; nt < NT; ++nt) {
    const int col = bn + nt * 16 + (l & 15);
    float bv = BIAS_RELU ? bias[col] : 0.f;
#pragma unroll
    for (int r = 0; r < 4; ++r) {
      const int row = bm + wm * 16 + (l >> 4) * 4 + r;
      if (row < M) {
        float v = acc[nt][r];
        if (BIAS_RELU) v = fmaxf(v + bv, 0.f);
        C[(long long)row * Nn + col] = f2b(v);
      }
    }
  }
}

// ---------------------------------------------------------------------------
// Single-pass flash-style softmax + gather-aggregate. One 16-lane group per
// node. Index stream read as uint4 (8 edges per load, segment 8-aligned with
// zeroed pads). Unroll-8 body: 8 independent 256B row loads in flight.
// Masked final iteration (e=-inf => p=0 for pad slots). Deferred-max thr 8.
// (R9 version — VGPR 20 / high occupancy; R10's prefetch variant regressed.)
// ---------------------------------------------------------------------------
template <bool BIAS_RELU, bool OUT_BF16>
__global__ __launch_bounds__(256) void gat_aggregate(
    const int2* __restrict__ rowbe, const unsigned short* __restrict__ csr,
    const float* __restrict__ as, const float* __restrict__ ad,
    const unsigned short* __restrict__ h, const float* __restrict__ bias,
    void* __restrict__ outp, int Nn) {
  constexpr int F = 128;
  const int node = blockIdx.x * 16 + (threadIdx.x >> 4);
  const int hl = threadIdx.x & 15;
  if (node >= Nn) return;
  const int2 be = rowbe[node];
  const int beg = be.x, end = be.y;
  const float adn = ad[node];
  const int f0 = hl * 8;

  // self-loop seed
  float m = leaky(as[node] + adn);
  float sg = 1.f;
  float acc[8];
  {
    uint4 w = *(const uint4*)(h + (long long)node * F + f0);
    acc[0] = blo(w.x); acc[1] = bhi(w.x);
    acc[2] = blo(w.y); acc[3] = bhi(w.y);
    acc[4] = blo(w.z); acc[5] = bhi(w.z);
    acc[6] = blo(w.w); acc[7] = bhi(w.w);
  }

  int t = beg;
  // full unroll-8 iterations
  for (; t + 8 <= end; t += 8) {
    uint4 c = *(const uint4*)(csr + t);
    int s[8];
    s[0] = c.x & 0xFFFF; s[1] = c.x >> 16;
    s[2] = c.y & 0xFFFF; s[3] = c.y >> 16;
    s[4] = c.z & 0xFFFF; s[5] = c.z >> 16;
    s[6] = c.w & 0xFFFF; s[7] = c.w >> 16;
    uint4 w[8];
#pragma unroll
    for (int i = 0; i < 8; ++i)
      w[i] = *(const uint4*)(h + (long long)s[i] * F + f0);
    float e[8];
#pragma unroll
    for (int i = 0; i < 8; ++i) e[i] = leaky(as[s[i]] + adn);
    float em = e[0];
#pragma unroll
    for (int i = 1; i < 8; ++i) em = fmaxf(em, e[i]);
    if (em > m + 8.f) {
      float sc = __expf(m - em);
      sg *= sc;
#pragma unroll
      for (int j = 0; j < 8; ++j) acc[j] *= sc;
      m = em;
    }
    float p[8];
#pragma unroll
    for (int i = 0; i < 8; ++i) p[i] = __expf(e[i] - m);
#pragma unroll
    for (int i = 0; i < 8; ++i) sg += p[i];
#pragma unroll
    for (int i = 0; i < 8; ++i) {
      acc[0] += p[i] * blo(w[i].x); acc[1] += p[i] * bhi(w[i].x);
      acc[2] += p[i] * blo(w[i].y); acc[3] += p[i] * bhi(w[i].y);
      acc[4] += p[i] * blo(w[i].z); acc[5] += p[i] * bhi(w[i].z);
      acc[6] += p[i] * blo(w[i].w); acc[7] += p[i] * bhi(w[i].w);
    }
  }
  // masked final iteration (pads are zeroed indices; e forced to -inf)
  if (t < end) {
    uint4 c = *(const uint4*)(csr + t);
    int s[8];
    s[0] = c.x & 0xFFFF; s[1] = c.x >> 16;
    s[2] = c.y & 0xFFFF; s[3] = c.y >> 16;
    s[4] = c.z & 0xFFFF; s[5] = c.z >> 16;
    s[6] = c.w & 0xFFFF; s[7] = c.w >> 16;
    uint4 w[8];
#pragma unroll
    for (int i = 0; i < 8; ++i)
      w[i] = *(const uint4*)(h + (long long)s[i] * F + f0);
    float e[8];
#pragma unroll
    for (int i = 0; i < 8; ++i)
      e[i] = (t + i < end) ? leaky(as[s[i]] + adn) : -3.4e38f;
    float em = e[0];
#pragma unroll
    for (int i = 1; i < 8; ++i) em = fmaxf(em, e[i]);
    if (em > m + 8.f) {
      float sc = __expf(m - em);
      sg *= sc;
#pragma unroll
      for (int j = 0; j < 8; ++j) acc[j] *= sc;
      m = em;
    }
    float p[8];
#pragma unroll
    for (int i = 0; i < 8; ++i) p[i] = __expf(e[i] - m);
#pragma unroll
    for (int i = 0; i < 8; ++i) sg += p[i];
#pragma unroll
    for (int i = 0; i < 8; ++i) {
      acc[0] += p[i] * blo(w[i].x); acc[1] += p[i] * bhi(w[i].x);
      acc[2] += p[i] * blo(w[i].y); acc[3] += p[i] * bhi(w[i].y);
      acc[4] += p[i] * blo(w[i].z); acc[5] += p[i] * bhi(w[i].z);
      acc[6] += p[i] * blo(w[i].w); acc[7] += p[i] * bhi(w[i].w);
    }
  }

  const float inv = 1.f / (sg + 1e-16f);
#pragma unroll
  for (int j = 0; j < 8; ++j) {
    acc[j] *= inv;
    if (BIAS_RELU) acc[j] = fmaxf(acc[j] + bias[f0 + j], 0.f);
  }
  if (OUT_BF16) {
    short8 o;
#pragma unroll
    for (int j = 0; j < 8; ++j) o[j] = (short)f2b(acc[j]);
    *(short8*)((unsigned short*)outp + (long long)node * F + f0) = o;
  } else {
    float4 o0 = {acc[0], acc[1], acc[2], acc[3]};
    float4 o1 = {acc[4], acc[5], acc[6], acc[7]};
    float* orow = (float*)outp + (long long)node * F + f0;
    *(float4*)(orow) = o0;
    *(float4*)(orow + 4) = o1;
  }
}

extern "C" void kernel_launch(void* const* d_in, const int* in_sizes, int n_in,
                              void* d_out, int out_size, void* d_ws,
                              size_t ws_size, hipStream_t stream) {
  const float* x      = (const float*)d_in[0];
  const void*  ei     = d_in[1];
  const float* W1     = (const float*)d_in[2];
  const float* a1_src = (const float*)d_in[3];
  const float* a1_dst = (const float*)d_in[4];
  const float* b1     = (const float*)d_in[5];
  const float* W2     = (const float*)d_in[6];
  const float* a2_src = (const float*)d_in[7];
  const float* a2_dst = (const float*)d_in[8];
  const float* b2     = (const float*)d_in[9];
  float* out = (float*)d_out;

  const int N = 50000, E = 800000, IN = 128, HID = 256, OUT = 128;
  const int NBLK_E = (E + 2047) / 2048;
  const int NB = (N + 127) >> 7;
  const int nb4 = (N + 3) / 4;
  const int nb16 = (N + 15) / 16;

  char* ws = (char*)d_ws;
  size_t off = 0;
  auto carve = [&](size_t bytes) -> void* {
    void* p = ws + off;
    off = (off + bytes + 255) & ~(size_t)255;
    return p;
  };
  unsigned short* xb     = (unsigned short*)carve((size_t)N * IN * 2);
  unsigned short* aggx   = (unsigned short*)carve((size_t)N * IN * 2);
  unsigned short* out1   = (unsigned short*)carve((size_t)N * HID * 2);
  unsigned short* h2     = (unsigned short*)carve((size_t)N * OUT * 2);
  unsigned short* Wp1    = (unsigned short*)carve((size_t)IN * HID * 2);
  unsigned short* Wp2    = (unsigned short*)carve((size_t)HID * OUT * 2);
  float*          wa     = (float*)carve(768 * 4);
  unsigned int*   binned = (unsigned int*)carve((size_t)NB * BSTRIDE * 4);
  unsigned short* csr    = (unsigned short*)carve((size_t)NB * BSTRIDE * 2);
  int*            bcur   = (int*)carve(512 * 4);
  int2*           rowbe  = (int2*)carve((size_t)N * 8);
  float*          as_    = (float*)carve((size_t)N * 4);
  float*          ad_    = (float*)carve((size_t)N * 4);
  float*          as2_   = (float*)carve((size_t)N * 4);
  float*          ad2_   = (float*)carve((size_t)N * 4);
  int*            flag64 = (int*)carve(256);
  (void)ws_size; (void)in_sizes; (void)n_in; (void)out_size;

  // ---- prep (weights pack + matvecs + bcur zero + idx64 detect) ----
  prep_all<<<260, 256, 0, stream>>>(W1, W2, a1_src, a1_dst, a2_src, a2_dst,
                                    Wp1, Wp2, wa, bcur, ei, flag64);

  // ---- fused: edge binning + layer-1 scores/cast ----
  bin_and_alpha<<<NBLK_E + nb4, 256, 0, stream>>>(
      ei, flag64, E, bcur, binned, NBLK_E, x, wa, xb, as_, ad_, N);

  // ---- CSR finalize (8-aligned, zero-padded segments) ----
  place_csr<<<NB, 256, 0, stream>>>(binned, bcur, rowbe, csr, N);

  // ---- layer 1: aggregate x, GEMM(+bias+ReLU), BN=128 ----
  gat_aggregate<false, true><<<nb16, 256, 0, stream>>>(rowbe, csr, as_, ad_,
                                                       xb, nullptr, aggx, N);
  {
    dim3 g((N + 63) / 64, HID / 128);
    gemm_mfma<HID, IN, 8, true, false><<<g, 256, 0, stream>>>(
        aggx, Wp1, out1, N, b1, nullptr, nullptr, nullptr, nullptr);
  }

  // ---- layer 2: GEMM BN=128 (+deterministic fused scores), aggregate ----
  {
    dim3 g((N + 63) / 64, OUT / 128);
    gemm_mfma<OUT, HID, 8, false, true><<<g, 256, 0, stream>>>(
        out1, Wp2, h2, N, nullptr, wa + 256, wa + 512, as2_, ad2_);
  }
  gat_aggregate<true, false><<<nb16, 256, 0, stream>>>(rowbe, csr, as2_,
                                                       ad2_, h2, b2, out, N);
}